// Round 9
// baseline (200.776 us; speedup 1.0000x reference)
//
#include <hip/hip_runtime.h>
#include <math.h>

// ============================================================================
// ROUND 9 = MEASUREMENT ROUND. Identical to round 8 except main_kernel is
// launched 4x (deterministic, identical writes). dur_delta vs r8 (70.2us)
// = 3 * main_dur. This decides: attack main vs attack overhead vs declare.
// ============================================================================

constexpr int B = 32, S = 4096, I = 512, H = 512;
constexpr int CH = 128;          // s-positions per workgroup in main pass
constexpr int NCH = S / CH;      // 32 chunks per batch row
constexpr float NEGV = -1e18f;

// workspace layout (float offsets)
constexpr size_t WS_WKD   = 0;       // [512]  Wk^T @ Wout
constexpr size_t WS_WQD   = 512;     // [512]  Wq^T @ Wout
constexpr size_t WS_CC    = 1024;    // [1]    (bq+bk)·Wout
constexpr size_t WS_PARTS = 2048;    // [B*NCH*514] m,l,ctx[512] main partials

// ---------------------------------------------------------------------------
// prep: 17 blocks. 0..7 -> wkd 64-col tiles, 8..15 -> wqd, 16 -> cc.
// Column-dot over h: 16 loads batched into registers per round (16 in flight).
// ---------------------------------------------------------------------------
__global__ __launch_bounds__(256) void prep_kernel(
    const float* __restrict__ Wq, const float* __restrict__ bq,
    const float* __restrict__ Wk, const float* __restrict__ bk,
    const float* __restrict__ Wout, float* __restrict__ ws) {
  __shared__ float sh[256];
  int blk = blockIdx.x;
  int t = threadIdx.x, wv = t >> 6, ln = t & 63;

  if (blk < 16) {
    bool isQ = blk >= 8;
    const float* W = isQ ? Wq : Wk;
    float* out = ws + (isQ ? WS_WQD : WS_WKD);
    int j = (blk & 7) * 64 + ln;
    int h0 = wv * 128;
    float p = 0.f;
    for (int hb = 0; hb < 128; hb += 16) {
      float v[16];
      #pragma unroll
      for (int r = 0; r < 16; ++r)
        v[r] = W[(size_t)(h0 + hb + r) * I + j];
      #pragma unroll
      for (int r = 0; r < 16; ++r)
        p = fmaf(v[r], Wout[h0 + hb + r], p);
    }
    sh[wv * 64 + ln] = p;
    __syncthreads();
    if (t < 64) out[(blk & 7) * 64 + t] = sh[t] + sh[64 + t] + sh[128 + t] + sh[192 + t];
  } else {
    float p = 0.f;
    for (int h = t; h < H; h += 256) p = fmaf(bq[h] + bk[h], Wout[h], p);
    sh[t] = p;
    __syncthreads();
    for (int o = 128; o; o >>= 1) {
      if (t < o) sh[t] += sh[t + o];
      __syncthreads();
    }
    if (t == 0) ws[WS_CC] = sh[0];
  }
}

// ---------------------------------------------------------------------------
// main: one pass over key. 4 waves/block, 2 rows/wave/iter, 16 iters.
// Depth-2 register pipeline (8 dwordx4 = 8 KB in flight per wave).
// __launch_bounds__(256,4): 128-VGPR cap. (256,8) squeezed to 32 VGPR and
// spilled everything -> 473 MB scratch traffic, 2.1 TB/s. Do not raise.
// ---------------------------------------------------------------------------
__global__ __launch_bounds__(256, 4) void main_kernel(
    const float* __restrict__ query,
    const float* __restrict__ key, const int* __restrict__ mask,
    float* __restrict__ ws, float* __restrict__ attn_w) {
  const float* wkd = ws + WS_WKD;
  const float* wqd = ws + WS_WQD;
  float* parts = ws + WS_PARTS;

  int b = blockIdx.x, cidx = blockIdx.y;
  int t = threadIdx.x, wv = t >> 6, ln = t & 63;

  // per-wave redundant off[b] = query[b,:]·wqd + cc   (L2-hot)
  float offb;
  {
    const float* qb = query + (size_t)b * I;
    float p = qb[ln] * wqd[ln];
    #pragma unroll
    for (int k = 1; k < 8; ++k)
      p = fmaf(qb[ln + 64 * k], wqd[ln + 64 * k], p);
    #pragma unroll
    for (int o = 32; o; o >>= 1) p += __shfl_xor(p, o, 64);
    offb = p + ws[WS_CC];
  }

  const float* kb = key + ((size_t)b * S + (size_t)cidx * CH) * I;
  const int* mrow = mask + (size_t)b * S + cidx * CH;
  float* awrow = attn_w + (size_t)b * S + cidx * CH;

  float4 wA = *(const float4*)(wkd + ln * 4);
  float4 wB = *(const float4*)(wkd + 256 + ln * 4);

  float m = -INFINITY, l = 0.f;
  float4 cA = {0.f, 0.f, 0.f, 0.f}, cB = {0.f, 0.f, 0.f, 0.f};

  constexpr int NIT = CH / 8;        // 16 iterations
  const float* lanep = kb + (size_t)(wv * 2) * I + ln * 4;
  constexpr int ROWSTEP = 8 * I;     // floats per iteration step

  // prologue: iters 0 (u) and 1 (v)
  float4 uA0 = *(const float4*)(lanep);
  float4 uB0 = *(const float4*)(lanep + 256);
  float4 uA1 = *(const float4*)(lanep + 512);
  float4 uB1 = *(const float4*)(lanep + 768);
  float4 vA0 = *(const float4*)(lanep + ROWSTEP);
  float4 vB0 = *(const float4*)(lanep + ROWSTEP + 256);
  float4 vA1 = *(const float4*)(lanep + ROWSTEP + 512);
  float4 vB1 = *(const float4*)(lanep + ROWSTEP + 768);

  #pragma unroll 2
  for (int it = 0; it < NIT; ++it) {
    int s = wv * 2 + it * 8;
    int itn = (it + 2 < NIT) ? it + 2 : it;   // clamped tail prefetch (L2-hot)
    const float* kn = lanep + (size_t)itn * ROWSTEP;
    float4 nA0 = *(const float4*)(kn);
    float4 nB0 = *(const float4*)(kn + 256);
    float4 nA1 = *(const float4*)(kn + 512);
    float4 nB1 = *(const float4*)(kn + 768);

    float d0 = uA0.x * wA.x, d1 = uA1.x * wA.x;
    d0 = fmaf(uA0.y, wA.y, d0); d1 = fmaf(uA1.y, wA.y, d1);
    d0 = fmaf(uA0.z, wA.z, d0); d1 = fmaf(uA1.z, wA.z, d1);
    d0 = fmaf(uA0.w, wA.w, d0); d1 = fmaf(uA1.w, wA.w, d1);
    d0 = fmaf(uB0.x, wB.x, d0); d1 = fmaf(uB1.x, wB.x, d1);
    d0 = fmaf(uB0.y, wB.y, d0); d1 = fmaf(uB1.y, wB.y, d1);
    d0 = fmaf(uB0.z, wB.z, d0); d1 = fmaf(uB1.z, wB.z, d1);
    d0 = fmaf(uB0.w, wB.w, d0); d1 = fmaf(uB1.w, wB.w, d1);
    #pragma unroll
    for (int o = 32; o; o >>= 1) {
      d0 += __shfl_xor(d0, o, 64);
      d1 += __shfl_xor(d1, o, 64);
    }

    int2 mm = *(const int2*)(mrow + s);
    float s0 = mm.x ? NEGV : (offb + d0);
    float s1 = mm.y ? NEGV : (offb + d1);
    if (ln == 0) *(float2*)(awrow + s) = float2{s0, s1};

    float mx = fmaxf(s0, s1);
    if (mx > m) {                               // wave-uniform, rare
      float sc = __expf(m - mx);                // exp(-inf)=0 handles init
      l *= sc;
      cA.x *= sc; cA.y *= sc; cA.z *= sc; cA.w *= sc;
      cB.x *= sc; cB.y *= sc; cB.z *= sc; cB.w *= sc;
      m = mx;
    }
    float e0 = __expf(s0 - m);
    float e1 = __expf(s1 - m);
    l += e0 + e1;
    cA.x = fmaf(e0, uA0.x, fmaf(e1, uA1.x, cA.x));
    cA.y = fmaf(e0, uA0.y, fmaf(e1, uA1.y, cA.y));
    cA.z = fmaf(e0, uA0.z, fmaf(e1, uA1.z, cA.z));
    cA.w = fmaf(e0, uA0.w, fmaf(e1, uA1.w, cA.w));
    cB.x = fmaf(e0, uB0.x, fmaf(e1, uB1.x, cB.x));
    cB.y = fmaf(e0, uB0.y, fmaf(e1, uB1.y, cB.y));
    cB.z = fmaf(e0, uB0.z, fmaf(e1, uB1.z, cB.z));
    cB.w = fmaf(e0, uB0.w, fmaf(e1, uB1.w, cB.w));

    // rotate pipeline registers (renamed away by the unroll)
    uA0 = vA0; uB0 = vB0; uA1 = vA1; uB1 = vB1;
    vA0 = nA0; vB0 = nB0; vA1 = nA1; vB1 = nB1;
  }

  // combine the 4 waves' online states into one block partial
  __shared__ float shm[4], shl[4];
  __shared__ float shc[4][512];
  if (ln == 0) { shm[wv] = m; shl[wv] = l; }
  *(float4*)&shc[wv][ln * 4] = cA;
  *(float4*)&shc[wv][256 + ln * 4] = cB;
  __syncthreads();

  float mb = fmaxf(fmaxf(shm[0], shm[1]), fmaxf(shm[2], shm[3]));
  float ew0 = __expf(shm[0] - mb), ew1 = __expf(shm[1] - mb);
  float ew2 = __expf(shm[2] - mb), ew3 = __expf(shm[3] - mb);
  float* slot = parts + ((size_t)b * NCH + cidx) * 514;
  if (t == 0) {
    slot[0] = mb;
    slot[1] = shl[0] * ew0 + shl[1] * ew1 + shl[2] * ew2 + shl[3] * ew3;
  }
  for (int i = t; i < I; i += 256) {
    float acc = shc[0][i] * ew0;
    acc = fmaf(shc[1][i], ew1, acc);
    acc = fmaf(shc[2][i], ew2, acc);
    acc = fmaf(shc[3][i], ew3, acc);
    slot[2 + i] = acc;
  }
}

// ---------------------------------------------------------------------------
// finish: grid (B, 8), 256 threads. ctx-combine then GEMV with 4 threads
// per Wk row (interleaved 16B chunks, full 64B lines), shfl_xor combine.
// ---------------------------------------------------------------------------
__global__ __launch_bounds__(256) void finish_kernel(
    const float* __restrict__ Wk, const float* __restrict__ bk,
    float* __restrict__ ws, float* __restrict__ attn) {
  const float* parts = ws + WS_PARTS;
  int b = blockIdx.x, hq = blockIdx.y, t = threadIdx.x;

  __shared__ float eld[NCH];
  __shared__ __align__(16) float ctx[I];
  const float* pb = parts + (size_t)b * NCH * 514;

  // every thread computes m, l (broadcast loads)
  float m = -INFINITY;
  #pragma unroll 8
  for (int p = 0; p < NCH; ++p) m = fmaxf(m, pb[p * 514]);
  float l = 0.f;
  #pragma unroll 8
  for (int p = 0; p < NCH; ++p) l = fmaf(pb[p * 514 + 1], __expf(pb[p * 514] - m), l);
  float invl = 1.f / l;
  if (t < NCH) eld[t] = __expf(pb[t * 514] - m) * invl;   // invl folded in
  __syncthreads();

  // ctx: thread owns i = t and i = t+256; NCH independent loads each
  {
    float a0 = 0.f, a1 = 0.f;
    #pragma unroll 8
    for (int p = 0; p < NCH; ++p) {
      float e = eld[p];
      a0 = fmaf(pb[p * 514 + 2 + t], e, a0);
      a1 = fmaf(pb[p * 514 + 258 + t], e, a1);
    }
    ctx[t] = a0;
    ctx[t + 256] = a1;
  }
  __syncthreads();

  // GEMV: h = hq*64 + t/4; quarter q = t&3 reads chunks q, q+4, q+8, ...
  int h = hq * 64 + (t >> 2), q = t & 3;
  const float4* wrow = (const float4*)(Wk + (size_t)h * I);
  const float4* cvec = (const float4*)ctx;
  float a0 = 0.f, a1 = 0.f;
  #pragma unroll 8
  for (int c = 0; c < 32; c += 2) {
    float4 w0 = wrow[q + 4 * c];
    float4 w1 = wrow[q + 4 * (c + 1)];
    float4 x0 = cvec[q + 4 * c];
    float4 x1 = cvec[q + 4 * (c + 1)];
    a0 = fmaf(w0.x, x0.x, fmaf(w0.y, x0.y, fmaf(w0.z, x0.z, fmaf(w0.w, x0.w, a0))));
    a1 = fmaf(w1.x, x1.x, fmaf(w1.y, x1.y, fmaf(w1.z, x1.z, fmaf(w1.w, x1.w, a1))));
  }
  float a = a0 + a1;
  a += __shfl_xor(a, 1, 64);
  a += __shfl_xor(a, 2, 64);
  if (q == 0) attn[(size_t)b * H + h] = a + bk[h];
}

// ---------------------------------------------------------------------------
extern "C" void kernel_launch(void* const* d_in, const int* in_sizes, int n_in,
                              void* d_out, int out_size, void* d_ws, size_t ws_size,
                              hipStream_t stream) {
  const float* query = (const float*)d_in[0];   // [B, I]
  const float* key   = (const float*)d_in[1];   // [B, S, I]
  const int*   mask  = (const int*)d_in[2];     // [B, S]
  const float* Wq    = (const float*)d_in[3];   // [H, I]
  const float* bq    = (const float*)d_in[4];   // [H]
  const float* Wk    = (const float*)d_in[5];   // [H, I]
  const float* bk    = (const float*)d_in[6];   // [H]
  const float* Wout  = (const float*)d_in[7];   // [H]

  float* attn   = (float*)d_out;                // [B, H]
  float* attn_w = (float*)d_out + (size_t)B * H;// [B, S]
  float* ws     = (float*)d_ws;

  prep_kernel<<<17, 256, 0, stream>>>(Wq, bq, Wk, bk, Wout, ws);
  // MEASUREMENT: 4x identical main launches (deterministic, same writes).
  // (dur - dur_r8) / 3 = true main_kernel duration.
  main_kernel<<<dim3(B, NCH), 256, 0, stream>>>(query, key, mask, ws, attn_w);
  main_kernel<<<dim3(B, NCH), 256, 0, stream>>>(query, key, mask, ws, attn_w);
  main_kernel<<<dim3(B, NCH), 256, 0, stream>>>(query, key, mask, ws, attn_w);
  main_kernel<<<dim3(B, NCH), 256, 0, stream>>>(query, key, mask, ws, attn_w);
  finish_kernel<<<dim3(B, 8), 256, 0, stream>>>(Wk, bk, ws, attn);
}

// Round 10
// 139.568 us; speedup vs baseline: 1.4386x; 1.4386x over previous
//
#include <hip/hip_runtime.h>
#include <math.h>

constexpr int B = 32, S = 4096, I = 512, H = 512;
constexpr int CH = 128;          // s-positions per workgroup in main pass
constexpr int NCH = S / CH;      // 32 chunks per batch row
constexpr int NFIN = 8;          // finisher blocks per batch (last 8 arrivals)
constexpr float NEGV = -1e18f;

// workspace layout (float offsets)
constexpr size_t WS_WKD   = 0;       // [512]  Wk^T @ Wout
constexpr size_t WS_WQD   = 512;     // [512]  Wq^T @ Wout
constexpr size_t WS_CC    = 1024;    // [1]    (bq+bk)·Wout
constexpr size_t WS_CNT   = 1056;    // [32]   per-batch arrival counters (int)
constexpr size_t WS_PARTS = 2048;    // [B*NCH*514] m,l,ctx[512] main partials

// ---------------------------------------------------------------------------
// prep: 17 blocks. 0..7 -> wkd 64-col tiles, 8..15 -> wqd, 16 -> cc + zero
// the per-batch counters. Column-dot over h with 32 loads batched into
// registers per round (4 latency rounds instead of 8).
// ---------------------------------------------------------------------------
__global__ __launch_bounds__(256) void prep_kernel(
    const float* __restrict__ Wq, const float* __restrict__ bq,
    const float* __restrict__ Wk, const float* __restrict__ bk,
    const float* __restrict__ Wout, float* __restrict__ ws) {
  __shared__ float sh[256];
  int blk = blockIdx.x;
  int t = threadIdx.x, wv = t >> 6, ln = t & 63;

  if (blk < 16) {
    bool isQ = blk >= 8;
    const float* W = isQ ? Wq : Wk;
    float* out = ws + (isQ ? WS_WQD : WS_WKD);
    int j = (blk & 7) * 64 + ln;
    int h0 = wv * 128;
    float p = 0.f;
    for (int hb = 0; hb < 128; hb += 32) {
      float v[32];
      #pragma unroll
      for (int r = 0; r < 32; ++r)
        v[r] = W[(size_t)(h0 + hb + r) * I + j];
      #pragma unroll
      for (int r = 0; r < 32; ++r)
        p = fmaf(v[r], Wout[h0 + hb + r], p);
    }
    sh[wv * 64 + ln] = p;
    __syncthreads();
    if (t < 64) out[(blk & 7) * 64 + t] = sh[t] + sh[64 + t] + sh[128 + t] + sh[192 + t];
  } else {
    // zero the arrival counters (re-done every call; replay-safe)
    if (t < B) ((int*)(ws + WS_CNT))[t] = 0;
    float p = 0.f;
    for (int h = t; h < H; h += 256) p = fmaf(bq[h] + bk[h], Wout[h], p);
    sh[t] = p;
    __syncthreads();
    for (int o = 128; o; o >>= 1) {
      if (t < o) sh[t] += sh[t + o];
      __syncthreads();
    }
    if (t == 0) ws[WS_CC] = sh[0];
  }
}

// ---------------------------------------------------------------------------
// main+finish fused. Main phase: one pass over key (4 waves/block, 2 rows/
// wave/iter, depth-2 register pipeline) -> per-block online-softmax partial.
// Epilogue: each block fences + bumps cnt[b]; the LAST 8 arrivals per batch
// spin until cnt[b]==NCH (grid = 1024 = exactly 4 blocks/CU x 256 CUs,
// co-resident via __launch_bounds__(256,4) -> spin is deadlock-free), then
// each does one 64-row slice of the ctx-combine + Wk-row GEMV.
// (256,8) squeezed to 32 VGPR and spilled (473 MB scratch, 2.1 TB/s): keep 4.
// ---------------------------------------------------------------------------
__global__ __launch_bounds__(256, 4) void main_kernel(
    const float* __restrict__ query,
    const float* __restrict__ key, const int* __restrict__ mask,
    const float* __restrict__ Wk, const float* __restrict__ bk,
    float* __restrict__ ws, float* __restrict__ attn_w,
    float* __restrict__ attn) {
  const float* wkd = ws + WS_WKD;
  const float* wqd = ws + WS_WQD;
  float* parts = ws + WS_PARTS;

  int b = blockIdx.x, cidx = blockIdx.y;
  int t = threadIdx.x, wv = t >> 6, ln = t & 63;

  // per-wave redundant off[b] = query[b,:]·wqd + cc   (L2-hot)
  float offb;
  {
    const float* qb = query + (size_t)b * I;
    float p = qb[ln] * wqd[ln];
    #pragma unroll
    for (int k = 1; k < 8; ++k)
      p = fmaf(qb[ln + 64 * k], wqd[ln + 64 * k], p);
    #pragma unroll
    for (int o = 32; o; o >>= 1) p += __shfl_xor(p, o, 64);
    offb = p + ws[WS_CC];
  }

  const float* kb = key + ((size_t)b * S + (size_t)cidx * CH) * I;
  const int* mrow = mask + (size_t)b * S + cidx * CH;
  float* awrow = attn_w + (size_t)b * S + cidx * CH;

  float4 wA = *(const float4*)(wkd + ln * 4);
  float4 wB = *(const float4*)(wkd + 256 + ln * 4);

  float m = -INFINITY, l = 0.f;
  float4 cA = {0.f, 0.f, 0.f, 0.f}, cB = {0.f, 0.f, 0.f, 0.f};

  constexpr int NIT = CH / 8;        // 16 iterations
  const float* lanep = kb + (size_t)(wv * 2) * I + ln * 4;
  constexpr int ROWSTEP = 8 * I;     // floats per iteration step

  // prologue: iters 0 (u) and 1 (v)
  float4 uA0 = *(const float4*)(lanep);
  float4 uB0 = *(const float4*)(lanep + 256);
  float4 uA1 = *(const float4*)(lanep + 512);
  float4 uB1 = *(const float4*)(lanep + 768);
  float4 vA0 = *(const float4*)(lanep + ROWSTEP);
  float4 vB0 = *(const float4*)(lanep + ROWSTEP + 256);
  float4 vA1 = *(const float4*)(lanep + ROWSTEP + 512);
  float4 vB1 = *(const float4*)(lanep + ROWSTEP + 768);

  #pragma unroll 2
  for (int it = 0; it < NIT; ++it) {
    int s = wv * 2 + it * 8;
    int itn = (it + 2 < NIT) ? it + 2 : it;   // clamped tail prefetch (L2-hot)
    const float* kn = lanep + (size_t)itn * ROWSTEP;
    float4 nA0 = *(const float4*)(kn);
    float4 nB0 = *(const float4*)(kn + 256);
    float4 nA1 = *(const float4*)(kn + 512);
    float4 nB1 = *(const float4*)(kn + 768);

    float d0 = uA0.x * wA.x, d1 = uA1.x * wA.x;
    d0 = fmaf(uA0.y, wA.y, d0); d1 = fmaf(uA1.y, wA.y, d1);
    d0 = fmaf(uA0.z, wA.z, d0); d1 = fmaf(uA1.z, wA.z, d1);
    d0 = fmaf(uA0.w, wA.w, d0); d1 = fmaf(uA1.w, wA.w, d1);
    d0 = fmaf(uB0.x, wB.x, d0); d1 = fmaf(uB1.x, wB.x, d1);
    d0 = fmaf(uB0.y, wB.y, d0); d1 = fmaf(uB1.y, wB.y, d1);
    d0 = fmaf(uB0.z, wB.z, d0); d1 = fmaf(uB1.z, wB.z, d1);
    d0 = fmaf(uB0.w, wB.w, d0); d1 = fmaf(uB1.w, wB.w, d1);
    #pragma unroll
    for (int o = 32; o; o >>= 1) {
      d0 += __shfl_xor(d0, o, 64);
      d1 += __shfl_xor(d1, o, 64);
    }

    int2 mm = *(const int2*)(mrow + s);
    float s0 = mm.x ? NEGV : (offb + d0);
    float s1 = mm.y ? NEGV : (offb + d1);
    if (ln == 0) *(float2*)(awrow + s) = float2{s0, s1};

    float mx = fmaxf(s0, s1);
    if (mx > m) {                               // wave-uniform, rare
      float sc = __expf(m - mx);                // exp(-inf)=0 handles init
      l *= sc;
      cA.x *= sc; cA.y *= sc; cA.z *= sc; cA.w *= sc;
      cB.x *= sc; cB.y *= sc; cB.z *= sc; cB.w *= sc;
      m = mx;
    }
    float e0 = __expf(s0 - m);
    float e1 = __expf(s1 - m);
    l += e0 + e1;
    cA.x = fmaf(e0, uA0.x, fmaf(e1, uA1.x, cA.x));
    cA.y = fmaf(e0, uA0.y, fmaf(e1, uA1.y, cA.y));
    cA.z = fmaf(e0, uA0.z, fmaf(e1, uA1.z, cA.z));
    cA.w = fmaf(e0, uA0.w, fmaf(e1, uA1.w, cA.w));
    cB.x = fmaf(e0, uB0.x, fmaf(e1, uB1.x, cB.x));
    cB.y = fmaf(e0, uB0.y, fmaf(e1, uB1.y, cB.y));
    cB.z = fmaf(e0, uB0.z, fmaf(e1, uB1.z, cB.z));
    cB.w = fmaf(e0, uB0.w, fmaf(e1, uB1.w, cB.w));

    // rotate pipeline registers (renamed away by the unroll)
    uA0 = vA0; uB0 = vB0; uA1 = vA1; uB1 = vB1;
    vA0 = nA0; vB0 = nB0; vA1 = nA1; vB1 = nB1;
  }

  // combine the 4 waves' online states into one block partial
  __shared__ float shm[4], shl[4];
  __shared__ __align__(16) float shc[4][512];
  if (ln == 0) { shm[wv] = m; shl[wv] = l; }
  *(float4*)&shc[wv][ln * 4] = cA;
  *(float4*)&shc[wv][256 + ln * 4] = cB;
  __syncthreads();

  float mb = fmaxf(fmaxf(shm[0], shm[1]), fmaxf(shm[2], shm[3]));
  float ew0 = __expf(shm[0] - mb), ew1 = __expf(shm[1] - mb);
  float ew2 = __expf(shm[2] - mb), ew3 = __expf(shm[3] - mb);
  float* slot = parts + ((size_t)b * NCH + cidx) * 514;
  if (t == 0) {
    slot[0] = mb;
    slot[1] = shl[0] * ew0 + shl[1] * ew1 + shl[2] * ew2 + shl[3] * ew3;
  }
  for (int i = t; i < I; i += 256) {
    float acc = shc[0][i] * ew0;
    acc = fmaf(shc[1][i], ew1, acc);
    acc = fmaf(shc[2][i], ew2, acc);
    acc = fmaf(shc[3][i], ew3, acc);
    slot[2 + i] = acc;
  }

  // ---- fused finish: last NFIN arrivals per batch do one GEMV slice each ---
  __syncthreads();                    // slot stores drained (barrier implies waitcnt)
  __shared__ int svv;
  int* cntb = (int*)(ws + WS_CNT) + b;
  if (t == 0) {
    __threadfence();                  // make this block's slot device-visible
    svv = atomicAdd(cntb, 1);
  }
  __syncthreads();
  int v = svv;
  if (v < NCH - NFIN) return;         // not a finisher
  int hq = v - (NCH - NFIN);          // slice id 0..7 (arrival-order-independent work)

  if (t == 0) {
    while (__hip_atomic_load(cntb, __ATOMIC_ACQUIRE, __HIP_MEMORY_SCOPE_AGENT) < NCH)
      __builtin_amdgcn_s_sleep(2);
  }
  __syncthreads();
  __threadfence();                    // acquire: invalidate caches before reading parts

  const float* pb = parts + (size_t)b * NCH * 514;
  float* eld = &shc[0][0];            // reuse main-phase LDS
  float* ctx = &shc[1][0];            // 512 floats, 16B-aligned

  float m2 = -INFINITY;
  #pragma unroll 8
  for (int p = 0; p < NCH; ++p) m2 = fmaxf(m2, pb[p * 514]);
  float l2 = 0.f;
  #pragma unroll 8
  for (int p = 0; p < NCH; ++p) l2 = fmaf(pb[p * 514 + 1], __expf(pb[p * 514] - m2), l2);
  float invl = 1.f / l2;
  if (t < NCH) eld[t] = __expf(pb[t * 514] - m2) * invl;   // invl folded in
  __syncthreads();

  {
    float a0 = 0.f, a1 = 0.f;
    #pragma unroll 8
    for (int p = 0; p < NCH; ++p) {
      float e = eld[p];
      a0 = fmaf(pb[p * 514 + 2 + t], e, a0);
      a1 = fmaf(pb[p * 514 + 258 + t], e, a1);
    }
    ctx[t] = a0;
    ctx[t + 256] = a1;
  }
  __syncthreads();

  // GEMV slice: h = hq*64 + t/4; quarter q reads interleaved 16B chunks
  int h = hq * 64 + (t >> 2), q = t & 3;
  const float4* wrow = (const float4*)(Wk + (size_t)h * I);
  const float4* cvec = (const float4*)ctx;
  float a0 = 0.f, a1 = 0.f;
  #pragma unroll 8
  for (int c = 0; c < 32; c += 2) {
    float4 w0 = wrow[q + 4 * c];
    float4 w1 = wrow[q + 4 * (c + 1)];
    float4 x0 = cvec[q + 4 * c];
    float4 x1 = cvec[q + 4 * (c + 1)];
    a0 = fmaf(w0.x, x0.x, fmaf(w0.y, x0.y, fmaf(w0.z, x0.z, fmaf(w0.w, x0.w, a0))));
    a1 = fmaf(w1.x, x1.x, fmaf(w1.y, x1.y, fmaf(w1.z, x1.z, fmaf(w1.w, x1.w, a1))));
  }
  float a = a0 + a1;
  a += __shfl_xor(a, 1, 64);
  a += __shfl_xor(a, 2, 64);
  if (q == 0) attn[(size_t)b * H + h] = a + bk[h];
}

// ---------------------------------------------------------------------------
extern "C" void kernel_launch(void* const* d_in, const int* in_sizes, int n_in,
                              void* d_out, int out_size, void* d_ws, size_t ws_size,
                              hipStream_t stream) {
  const float* query = (const float*)d_in[0];   // [B, I]
  const float* key   = (const float*)d_in[1];   // [B, S, I]
  const int*   mask  = (const int*)d_in[2];     // [B, S]
  const float* Wq    = (const float*)d_in[3];   // [H, I]
  const float* bq    = (const float*)d_in[4];   // [H]
  const float* Wk    = (const float*)d_in[5];   // [H, I]
  const float* bk    = (const float*)d_in[6];   // [H]
  const float* Wout  = (const float*)d_in[7];   // [H]

  float* attn   = (float*)d_out;                // [B, H]
  float* attn_w = (float*)d_out + (size_t)B * H;// [B, S]
  float* ws     = (float*)d_ws;

  prep_kernel<<<17, 256, 0, stream>>>(Wq, bq, Wk, bk, Wout, ws);
  main_kernel<<<dim3(B, NCH), 256, 0, stream>>>(query, key, mask, Wk, bk,
                                                ws, attn_w, attn);
}

// Round 11
// 107.110 us; speedup vs baseline: 1.8745x; 1.3030x over previous
//
#include <hip/hip_runtime.h>
#include <math.h>

constexpr int B = 32, S = 4096, I = 512, H = 512;
constexpr int CH = 256;          // s-positions per workgroup in main pass
constexpr int NCH = S / CH;      // 16 chunks per batch row
constexpr int NFIN = 8;          // finisher blocks per batch (last 8 arrivals)
constexpr float NEGV = -1e18f;

// workspace layout (float offsets)
constexpr size_t WS_WKD   = 0;       // [512]  Wk^T @ Wout
constexpr size_t WS_WQD   = 512;     // [512]  Wq^T @ Wout
constexpr size_t WS_CC    = 1024;    // [1]    (bq+bk)·Wout
constexpr size_t WS_CNT   = 1056;    // [32]   per-batch arrival counters (int)
constexpr size_t WS_PARTS = 2048;    // [B*NCH*514] m,l,ctx[512] main partials

// ---------------------------------------------------------------------------
// prep: 17 blocks. 0..7 -> wkd 64-col tiles, 8..15 -> wqd, 16 -> cc + zero
// counters. Column-dot over h with 32 loads batched into registers per round.
// ---------------------------------------------------------------------------
__global__ __launch_bounds__(256) void prep_kernel(
    const float* __restrict__ Wq, const float* __restrict__ bq,
    const float* __restrict__ Wk, const float* __restrict__ bk,
    const float* __restrict__ Wout, float* __restrict__ ws) {
  __shared__ float sh[256];
  int blk = blockIdx.x;
  int t = threadIdx.x, wv = t >> 6, ln = t & 63;

  if (blk < 16) {
    bool isQ = blk >= 8;
    const float* W = isQ ? Wq : Wk;
    float* out = ws + (isQ ? WS_WQD : WS_WKD);
    int j = (blk & 7) * 64 + ln;
    int h0 = wv * 128;
    float p = 0.f;
    for (int hb = 0; hb < 128; hb += 32) {
      float v[32];
      #pragma unroll
      for (int r = 0; r < 32; ++r)
        v[r] = W[(size_t)(h0 + hb + r) * I + j];
      #pragma unroll
      for (int r = 0; r < 32; ++r)
        p = fmaf(v[r], Wout[h0 + hb + r], p);
    }
    sh[wv * 64 + ln] = p;
    __syncthreads();
    if (t < 64) out[(blk & 7) * 64 + t] = sh[t] + sh[64 + t] + sh[128 + t] + sh[192 + t];
  } else {
    // zero the arrival counters (re-done every call; replay-safe)
    if (t < B) ((int*)(ws + WS_CNT))[t] = 0;
    float p = 0.f;
    for (int h = t; h < H; h += 256) p = fmaf(bq[h] + bk[h], Wout[h], p);
    sh[t] = p;
    __syncthreads();
    for (int o = 128; o; o >>= 1) {
      if (t < o) sh[t] += sh[t + o];
      __syncthreads();
    }
    if (t == 0) ws[WS_CC] = sh[0];
  }
}

// ---------------------------------------------------------------------------
// main+finish fused. Main phase: one HBM pass over key (4 waves/block,
// 2 rows/wave/iter, depth-2 register pipeline). Epilogue: release-fence +
// atomicAdd(cnt[b]); the LAST NFIN arrivals per batch become finishers.
// Spin protocol (r10 lesson): RELAXED agent loads (no L2 invalidate) with an
// ACQUIRE probe only every 32 sleeps -- r10's per-iteration acquire spin
// (L2-inv storm) collapsed BW to 0.8 TB/s. Grid 512 = <=2 blocks/CU vs
// 4-block capacity: full co-residency with 2x slack -> no deadlock.
// (256,8) squeezed to 32 VGPR and spilled (473 MB scratch): keep min-waves=4.
// ---------------------------------------------------------------------------
__global__ __launch_bounds__(256, 4) void main_kernel(
    const float* __restrict__ query,
    const float* __restrict__ key, const int* __restrict__ mask,
    const float* __restrict__ Wk, const float* __restrict__ bk,
    float* __restrict__ ws, float* __restrict__ attn_w,
    float* __restrict__ attn) {
  const float* wkd = ws + WS_WKD;
  const float* wqd = ws + WS_WQD;
  float* parts = ws + WS_PARTS;

  int b = blockIdx.x, cidx = blockIdx.y;
  int t = threadIdx.x, wv = t >> 6, ln = t & 63;

  // per-wave redundant off[b] = query[b,:]·wqd + cc   (L2-hot)
  float offb;
  {
    const float* qb = query + (size_t)b * I;
    float p = qb[ln] * wqd[ln];
    #pragma unroll
    for (int k = 1; k < 8; ++k)
      p = fmaf(qb[ln + 64 * k], wqd[ln + 64 * k], p);
    #pragma unroll
    for (int o = 32; o; o >>= 1) p += __shfl_xor(p, o, 64);
    offb = p + ws[WS_CC];
  }

  const float* kb = key + ((size_t)b * S + (size_t)cidx * CH) * I;
  const int* mrow = mask + (size_t)b * S + cidx * CH;
  float* awrow = attn_w + (size_t)b * S + cidx * CH;

  float4 wA = *(const float4*)(wkd + ln * 4);
  float4 wB = *(const float4*)(wkd + 256 + ln * 4);

  float m = -INFINITY, l = 0.f;
  float4 cA = {0.f, 0.f, 0.f, 0.f}, cB = {0.f, 0.f, 0.f, 0.f};

  constexpr int NIT = CH / 8;        // 32 iterations
  const float* lanep = kb + (size_t)(wv * 2) * I + ln * 4;
  constexpr int ROWSTEP = 8 * I;     // floats per iteration step

  // prologue: iters 0 (u) and 1 (v)
  float4 uA0 = *(const float4*)(lanep);
  float4 uB0 = *(const float4*)(lanep + 256);
  float4 uA1 = *(const float4*)(lanep + 512);
  float4 uB1 = *(const float4*)(lanep + 768);
  float4 vA0 = *(const float4*)(lanep + ROWSTEP);
  float4 vB0 = *(const float4*)(lanep + ROWSTEP + 256);
  float4 vA1 = *(const float4*)(lanep + ROWSTEP + 512);
  float4 vB1 = *(const float4*)(lanep + ROWSTEP + 768);

  #pragma unroll 2
  for (int it = 0; it < NIT; ++it) {
    int s = wv * 2 + it * 8;
    int itn = (it + 2 < NIT) ? it + 2 : it;   // clamped tail prefetch (L2-hot)
    const float* kn = lanep + (size_t)itn * ROWSTEP;
    float4 nA0 = *(const float4*)(kn);
    float4 nB0 = *(const float4*)(kn + 256);
    float4 nA1 = *(const float4*)(kn + 512);
    float4 nB1 = *(const float4*)(kn + 768);

    float d0 = uA0.x * wA.x, d1 = uA1.x * wA.x;
    d0 = fmaf(uA0.y, wA.y, d0); d1 = fmaf(uA1.y, wA.y, d1);
    d0 = fmaf(uA0.z, wA.z, d0); d1 = fmaf(uA1.z, wA.z, d1);
    d0 = fmaf(uA0.w, wA.w, d0); d1 = fmaf(uA1.w, wA.w, d1);
    d0 = fmaf(uB0.x, wB.x, d0); d1 = fmaf(uB1.x, wB.x, d1);
    d0 = fmaf(uB0.y, wB.y, d0); d1 = fmaf(uB1.y, wB.y, d1);
    d0 = fmaf(uB0.z, wB.z, d0); d1 = fmaf(uB1.z, wB.z, d1);
    d0 = fmaf(uB0.w, wB.w, d0); d1 = fmaf(uB1.w, wB.w, d1);
    #pragma unroll
    for (int o = 32; o; o >>= 1) {
      d0 += __shfl_xor(d0, o, 64);
      d1 += __shfl_xor(d1, o, 64);
    }

    int2 mm = *(const int2*)(mrow + s);
    float s0 = mm.x ? NEGV : (offb + d0);
    float s1 = mm.y ? NEGV : (offb + d1);
    if (ln == 0) *(float2*)(awrow + s) = float2{s0, s1};

    float mx = fmaxf(s0, s1);
    if (mx > m) {                               // wave-uniform, rare
      float sc = __expf(m - mx);                // exp(-inf)=0 handles init
      l *= sc;
      cA.x *= sc; cA.y *= sc; cA.z *= sc; cA.w *= sc;
      cB.x *= sc; cB.y *= sc; cB.z *= sc; cB.w *= sc;
      m = mx;
    }
    float e0 = __expf(s0 - m);
    float e1 = __expf(s1 - m);
    l += e0 + e1;
    cA.x = fmaf(e0, uA0.x, fmaf(e1, uA1.x, cA.x));
    cA.y = fmaf(e0, uA0.y, fmaf(e1, uA1.y, cA.y));
    cA.z = fmaf(e0, uA0.z, fmaf(e1, uA1.z, cA.z));
    cA.w = fmaf(e0, uA0.w, fmaf(e1, uA1.w, cA.w));
    cB.x = fmaf(e0, uB0.x, fmaf(e1, uB1.x, cB.x));
    cB.y = fmaf(e0, uB0.y, fmaf(e1, uB1.y, cB.y));
    cB.z = fmaf(e0, uB0.z, fmaf(e1, uB1.z, cB.z));
    cB.w = fmaf(e0, uB0.w, fmaf(e1, uB1.w, cB.w));

    // rotate pipeline registers (renamed away by the unroll)
    uA0 = vA0; uB0 = vB0; uA1 = vA1; uB1 = vB1;
    vA0 = nA0; vB0 = nB0; vA1 = nA1; vB1 = nB1;
  }

  // combine the 4 waves' online states into one block partial
  __shared__ float shm[4], shl[4];
  __shared__ __align__(16) float shc[4][512];
  if (ln == 0) { shm[wv] = m; shl[wv] = l; }
  *(float4*)&shc[wv][ln * 4] = cA;
  *(float4*)&shc[wv][256 + ln * 4] = cB;
  __syncthreads();

  float mb = fmaxf(fmaxf(shm[0], shm[1]), fmaxf(shm[2], shm[3]));
  float ew0 = __expf(shm[0] - mb), ew1 = __expf(shm[1] - mb);
  float ew2 = __expf(shm[2] - mb), ew3 = __expf(shm[3] - mb);
  float* slot = parts + ((size_t)b * NCH + cidx) * 514;
  if (t == 0) {
    slot[0] = mb;
    slot[1] = shl[0] * ew0 + shl[1] * ew1 + shl[2] * ew2 + shl[3] * ew3;
  }
  for (int i = t; i < I; i += 256) {
    float acc = shc[0][i] * ew0;
    acc = fmaf(shc[1][i], ew1, acc);
    acc = fmaf(shc[2][i], ew2, acc);
    acc = fmaf(shc[3][i], ew3, acc);
    slot[2 + i] = acc;
  }

  // ---- fused finish: last NFIN arrivals per batch do one GEMV slice each ---
  __syncthreads();                    // slot stores issued by all threads
  __shared__ int svv;
  int* cntb = (int*)(ws + WS_CNT) + b;
  if (t == 0) {
    __threadfence();                  // release: slot visible device-wide
    svv = atomicAdd(cntb, 1);
  }
  __syncthreads();
  int v = svv;
  if (v < NCH - NFIN) return;         // not a finisher
  int hq = v - (NCH - NFIN);          // slice id 0..7 (rank-determined work)

  if (t == 0) {
    // RELAXED spin (coherent fabric read, NO cache invalidate) + rare
    // ACQUIRE probe for guaranteed freshness. r10's acquire-every-iter
    // spin caused an L2-invalidate storm (0.8 TB/s device-wide).
    int itc = 0;
    while (true) {
      int c = __hip_atomic_load(cntb, __ATOMIC_RELAXED, __HIP_MEMORY_SCOPE_AGENT);
      if (c >= NCH) break;
      __builtin_amdgcn_s_sleep(8);
      if ((++itc & 31) == 0) {
        c = __hip_atomic_load(cntb, __ATOMIC_ACQUIRE, __HIP_MEMORY_SCOPE_AGENT);
        if (c >= NCH) break;
      }
    }
  }
  __syncthreads();
  __threadfence();                    // acquire: see all batches' slots

  const float* pb = parts + (size_t)b * NCH * 514;
  float* eld = &shc[0][0];            // reuse main-phase LDS
  float* ctx = &shc[1][0];            // 512 floats, 16B-aligned

  float m2 = -INFINITY;
  #pragma unroll
  for (int p = 0; p < NCH; ++p) m2 = fmaxf(m2, pb[p * 514]);
  float l2 = 0.f;
  #pragma unroll
  for (int p = 0; p < NCH; ++p) l2 = fmaf(pb[p * 514 + 1], __expf(pb[p * 514] - m2), l2);
  float invl = 1.f / l2;
  if (t < NCH) eld[t] = __expf(pb[t * 514] - m2) * invl;   // invl folded in
  __syncthreads();

  {
    float a0 = 0.f, a1 = 0.f;
    #pragma unroll
    for (int p = 0; p < NCH; ++p) {
      float e = eld[p];
      a0 = fmaf(pb[p * 514 + 2 + t], e, a0);
      a1 = fmaf(pb[p * 514 + 258 + t], e, a1);
    }
    ctx[t] = a0;
    ctx[t + 256] = a1;
  }
  __syncthreads();

  // GEMV slice: h = hq*64 + t/4; quarter q reads interleaved 16B chunks
  int h = hq * 64 + (t >> 2), q = t & 3;
  const float4* wrow = (const float4*)(Wk + (size_t)h * I);
  const float4* cvec = (const float4*)ctx;
  float a0 = 0.f, a1 = 0.f;
  #pragma unroll 8
  for (int c = 0; c < 32; c += 2) {
    float4 w0 = wrow[q + 4 * c];
    float4 w1 = wrow[q + 4 * (c + 1)];
    float4 x0 = cvec[q + 4 * c];
    float4 x1 = cvec[q + 4 * (c + 1)];
    a0 = fmaf(w0.x, x0.x, fmaf(w0.y, x0.y, fmaf(w0.z, x0.z, fmaf(w0.w, x0.w, a0))));
    a1 = fmaf(w1.x, x1.x, fmaf(w1.y, x1.y, fmaf(w1.z, x1.z, fmaf(w1.w, x1.w, a1))));
  }
  float a = a0 + a1;
  a += __shfl_xor(a, 1, 64);
  a += __shfl_xor(a, 2, 64);
  if (q == 0) attn[(size_t)b * H + h] = a + bk[h];
}

// ---------------------------------------------------------------------------
extern "C" void kernel_launch(void* const* d_in, const int* in_sizes, int n_in,
                              void* d_out, int out_size, void* d_ws, size_t ws_size,
                              hipStream_t stream) {
  const float* query = (const float*)d_in[0];   // [B, I]
  const float* key   = (const float*)d_in[1];   // [B, S, I]
  const int*   mask  = (const int*)d_in[2];     // [B, S]
  const float* Wq    = (const float*)d_in[3];   // [H, I]
  const float* bq    = (const float*)d_in[4];   // [H]
  const float* Wk    = (const float*)d_in[5];   // [H, I]
  const float* bk    = (const float*)d_in[6];   // [H]
  const float* Wout  = (const float*)d_in[7];   // [H]

  float* attn   = (float*)d_out;                // [B, H]
  float* attn_w = (float*)d_out + (size_t)B * H;// [B, S]
  float* ws     = (float*)d_ws;

  prep_kernel<<<17, 256, 0, stream>>>(Wq, bq, Wk, bk, Wout, ws);
  main_kernel<<<dim3(B, NCH), 256, 0, stream>>>(query, key, mask, Wk, bk,
                                                ws, attn_w, attn);
}